// Round 5
// baseline (191.224 us; speedup 1.0000x reference)
//
#include <hip/hip_runtime.h>

typedef unsigned short u16;
typedef unsigned char u8;
typedef __attribute__((ext_vector_type(8))) short short8;
typedef __attribute__((ext_vector_type(4))) short short4v;
typedef __attribute__((ext_vector_type(4))) float f32x4;

#define GLD16(g, l) __builtin_amdgcn_global_load_lds( \
    (const __attribute__((address_space(1))) void*)(g), \
    (__attribute__((address_space(3))) void*)(l), 16, 0, 0)

__device__ __forceinline__ float bf2f(u16 u){
  union { unsigned int i; float f; } v; v.i = ((unsigned int)u) << 16; return v.f;
}
__device__ __forceinline__ u16 f2bf(float f){
  union { float f; unsigned int i; } v; v.f = f;
  unsigned int u = v.i;
  unsigned int r = (u + 0x7FFFu + ((u >> 16) & 1u)) >> 16;
  return (u16)r;
}

__device__ __forceinline__ f32x4 mfma16(short4v a, short4v b, f32x4 c){
#if __has_builtin(__builtin_amdgcn_mfma_f32_16x16x16bf16_1k)
  return __builtin_amdgcn_mfma_f32_16x16x16bf16_1k(a, b, c, 0, 0, 0);
#else
  asm volatile("s_nop 1\n\tv_mfma_f32_16x16x16_bf16 %0, %1, %2, %0" : "+v"(c) : "v"(a), "v"(b));
  return c;
#endif
}

// ---------------- elementwise fp32 -> bf16 (x) ----------------
__global__ void cvt_k(const float* __restrict__ x, u16* __restrict__ o, int n4){
  int i = blockIdx.x * 256 + threadIdx.x;
  if (i >= n4) return;
  float4 v = ((const float4*)x)[i];
  unsigned long long pk = (unsigned long long)f2bf(v.x)
    | ((unsigned long long)f2bf(v.y) << 16)
    | ((unsigned long long)f2bf(v.z) << 32)
    | ((unsigned long long)f2bf(v.w) << 48);
  ((unsigned long long*)o)[i] = pk;
}

// ---------------- rel int32 -> u8 ----------------
__global__ void rel8_k(const int* __restrict__ r, u8* __restrict__ o, int n4){
  int i = blockIdx.x * 256 + threadIdx.x;
  if (i >= n4) return;
  int4 v = ((const int4*)r)[i];
  unsigned int pk = (unsigned int)(v.x & 255) | ((unsigned int)(v.y & 255) << 8)
    | ((unsigned int)(v.z & 255) << 16) | ((unsigned int)(v.w & 255) << 24);
  ((unsigned int*)o)[i] = pk;
}

// ---------------- transpose + convert weights: W[K,N] f32 -> Wt[N,K] bf16 ----------------
__global__ void tconv_k(const float* __restrict__ W, u16* __restrict__ Wt, int K, int N){
  __shared__ float tl[32][33];
  int n0 = blockIdx.x * 32, k0 = blockIdx.y * 32;
  for (int i = threadIdx.y; i < 32; i += 8)
    tl[i][threadIdx.x] = W[(size_t)(k0 + i) * N + n0 + threadIdx.x];
  __syncthreads();
  for (int i = threadIdx.y; i < 32; i += 8)
    Wt[(size_t)(n0 + i) * K + k0 + threadIdx.x] = f2bf(tl[threadIdx.x][i]);
}

// ---------------- bf16 GEMM (B^T input), BK=64, XOR-swizzled LDS ----------------
// MODE 0: scatter to q/k/v [B,H,S,D] bf16 (BN=128).  MODE 1: fp32 out (BN=64).
template<int BN, int MODE>
__global__ __launch_bounds__(256) void gemm_bt_k(const u16* __restrict__ A, const u16* __restrict__ Bt,
                                                 const float* __restrict__ bias,
                                                 u16* __restrict__ oq, u16* __restrict__ okk, u16* __restrict__ ov,
                                                 float* __restrict__ of,
                                                 int M, int N, int K){
  __shared__ u16 la[128 * 64];
  __shared__ u16 lb[BN * 64];
  const int t = threadIdx.x, w = t >> 6, lane = t & 63;
  const int l15 = lane & 15, l4 = lane >> 4;
  const int m0 = blockIdx.y * 128, n0 = blockIdx.x * BN;
  const int wr = w >> 1, wc = w & 1;
  constexpr int NI = BN / 32;
  f32x4 acc[4][NI] = {};
  const u16* Abase = A + (size_t)m0 * K;
  const u16* Bbase = Bt + (size_t)n0 * K;
  for (int kt = 0; kt < K; kt += 64){
    __syncthreads();
#pragma unroll
    for (int i = 0; i < 4; ++i){
      int chunk = i * 256 + t;
      int row = chunk >> 3, cs = chunk & 7;
      int c = cs ^ (row & 7);
      GLD16(Abase + (size_t)row * K + kt + c * 8, &la[(i * 256 + w * 64) * 8]);
    }
#pragma unroll
    for (int i = 0; i < BN / 32; ++i){
      int chunk = i * 256 + t;
      int row = chunk >> 3, cs = chunk & 7;
      int c = cs ^ (row & 7);
      GLD16(Bbase + (size_t)row * K + kt + c * 8, &lb[(i * 256 + w * 64) * 8]);
    }
    asm volatile("s_waitcnt vmcnt(0)" ::: "memory");
    __syncthreads();
    short8 af[4][2], bfr[NI][2];
#pragma unroll
    for (int mi = 0; mi < 4; ++mi){
      int row = wr * 64 + mi * 16 + l15;
#pragma unroll
      for (int h = 0; h < 2; ++h)
        af[mi][h] = *(const short8*)&la[row * 64 + (((h * 4 + l4) ^ (row & 7)) * 8)];
    }
#pragma unroll
    for (int ni = 0; ni < NI; ++ni){
      int row = wc * (BN / 2) + ni * 16 + l15;
#pragma unroll
      for (int h = 0; h < 2; ++h)
        bfr[ni][h] = *(const short8*)&lb[row * 64 + (((h * 4 + l4) ^ (row & 7)) * 8)];
    }
#pragma unroll
    for (int mi = 0; mi < 4; ++mi)
#pragma unroll
      for (int ni = 0; ni < NI; ++ni){
        acc[mi][ni] = __builtin_amdgcn_mfma_f32_16x16x32_bf16(af[mi][0], bfr[ni][0], acc[mi][ni], 0, 0, 0);
        acc[mi][ni] = __builtin_amdgcn_mfma_f32_16x16x32_bf16(af[mi][1], bfr[ni][1], acc[mi][ni], 0, 0, 0);
      }
  }
#pragma unroll
  for (int mi = 0; mi < 4; ++mi){
#pragma unroll
    for (int ni = 0; ni < NI; ++ni){
#pragma unroll
      for (int r = 0; r < 4; ++r){
        int m = m0 + wr * 64 + mi * 16 + l4 * 4 + r;
        int n = n0 + wc * (BN / 2) + ni * 16 + l15;
        float v = acc[mi][ni][r] + bias[n];
        if (MODE == 0){
          int tt = n >> 10, rr = n & 1023, head = rr >> 6, d = rr & 63;
          int b = m >> 11, s = m & 2047;
          u16* dst = (tt == 0) ? oq : (tt == 1) ? okk : ov;
          dst[(((size_t)(b * 16 + head)) * 2048 + s) * 64 + d] = f2bf(v);
        } else {
          of[(size_t)m * N + n] = v;
        }
      }
    }
  }
}

// ---------------- V transpose (k-field-permuted) + per-chunk column sums ----------------
__global__ __launch_bounds__(256) void transpose_v_k(const u16* __restrict__ vb, u16* __restrict__ vt,
                                                     float* __restrict__ vpart){
  __shared__ u16 tl[64][65];
  int bh = blockIdx.x >> 5, c = blockIdx.x & 31, s0 = c * 64;
  int t = threadIdx.x;
#pragma unroll
  for (int rsub = 0; rsub < 16; ++rsub){
    int idx = rsub * 256 + t;
    int i = idx >> 6, d = idx & 63;
    tl[i][d] = vb[(((size_t)bh * 2048) + s0 + i) * 64 + d];
  }
  __syncthreads();
#pragma unroll
  for (int rsub = 0; rsub < 16; ++rsub){
    int idx = rsub * 256 + t;
    int d = idx >> 6, j = idx & 63;
    int pj = (j & 3) | (((j >> 2) & 3) << 4) | (((j >> 4) & 3) << 2);
    vt[(((size_t)bh * 64) + d) * 2048 + s0 + pj] = tl[j][d];
  }
  if (t < 64){
    float s = 0.f;
#pragma unroll 8
    for (int j = 0; j < 64; ++j) s += bf2f(tl[j][t]);
    vpart[((size_t)bh * 32 + c) * 64 + t] = s;
  }
}

// ---------------- suffix scan over V chunk sums ----------------
__global__ void vsufscan_k(const float* __restrict__ vpart, float* __restrict__ vsuf){
  int bh = blockIdx.x, d = threadIdx.x;   // 64 threads
  float run = 0.f;
  vsuf[((size_t)bh * 33 + 32) * 64 + d] = 0.f;
  for (int c = 31; c >= 0; --c){
    run += vpart[((size_t)bh * 32 + c) * 64 + d];
    vsuf[((size_t)bh * 33 + c) * 64 + d] = run;
  }
}

// ---------------- fused rel-bias causal attention (8-wave split-K) ----------------
// Block = paired q-tiles (TA=qp, TB=31-qp), 512 threads. Group g = waves 0-3 /
// 4-7 processes virtual iters [0,17) / [17,33) of the 33. Fixed m=0 makes the
// cross-group combine a pure ADD of (acc, rsum); exactly one tile per pair
// needs it (TA<=16 -> B, TA>=17 -> A), done via LDS scratch aliasing dead Kt.
template<int U8>
__global__ __launch_bounds__(512, 4) void attn_k(const u16* __restrict__ qb, const u16* __restrict__ kb,
                                                 const u16* __restrict__ vt, const float* __restrict__ vsuf,
                                                 const void* __restrict__ relp, const float* __restrict__ rel_emb,
                                                 u16* __restrict__ ab){
  __shared__ u16 Kt[2][2][64 * 64];
  __shared__ u16 Vt[2][2][64 * 64];
  __shared__ float remb[64];
  __shared__ float scrsum[4][64];
  const int qp = blockIdx.x, bh = blockIdx.y;
  const int b = bh >> 4, h = bh & 15;
  const int TA = qp, TB = 31 - qp;
  const int q0A = TA * 64, q0B = TB * 64;
  const int tid = threadIdx.x;
  const int wv = tid >> 6, g = wv >> 2, w = wv & 3, lane = tid & 63;
  const int l15 = lane & 15, l4 = lane >> 4;
  const int tg = tid & 255;
  if (tid < 64) remb[tid] = rel_emb[tid * 16 + h] * (0.125f * 1.44269504088896f);
  const u16* kbh = kb + ((size_t)bh * 2048) * 64;
  const u16* vbh = vt + ((size_t)bh * 64) * 2048;
  const u16* qA = qb + (((size_t)bh * 2048) + q0A + w * 16 + l15) * 64 + l4 * 8;
  const u16* qB = qb + (((size_t)bh * 2048) + q0B + w * 16 + l15) * 64 + l4 * 8;
  const short8 aqA0 = *(const short8*)qA, aqA1 = *(const short8*)(qA + 32);
  const short8 aqB0 = *(const short8*)qB, aqB1 = *(const short8*)(qB + 32);
  const u8*  r8A  = (const u8*)relp + ((size_t)b * 2048 + q0A + w * 16 + l15) * 2048;
  const u8*  r8B  = (const u8*)relp + ((size_t)b * 2048 + q0B + w * 16 + l15) * 2048;
  const int* r32A = (const int*)relp + ((size_t)b * 2048 + q0A + w * 16 + l15) * 2048;
  const int* r32B = (const int*)relp + ((size_t)b * 2048 + q0B + w * 16 + l15) * 2048;

  const int srow0 = (tg >> 3), srow1 = 32 + (tg >> 3);
  const int scs = tg & 7;
  const int sc0 = scs ^ (srow0 & 7), sc1 = scs ^ (srow1 & 7);
  const int sldsoff = (w * 64) * 8;

#define STAGE(ktile, buf) do {                                                          \
    GLD16(kbh + (size_t)((ktile) * 64 + srow0) * 64 + sc0 * 8, &Kt[g][buf][sldsoff]);   \
    GLD16(kbh + (size_t)((ktile) * 64 + srow1) * 64 + sc1 * 8, &Kt[g][buf][2048 + sldsoff]); \
    GLD16(vbh + (size_t)srow0 * 2048 + (ktile) * 64 + sc0 * 8, &Vt[g][buf][sldsoff]);   \
    GLD16(vbh + (size_t)srow1 * 2048 + (ktile) * 64 + sc1 * 8, &Vt[g][buf][2048 + sldsoff]); \
  } while (0)

  f32x4 acc[4] = {};
  f32x4 accS[4] = {};
  float rsum = 0.f, rsumS = 0.f;
  unsigned int relc[4], reln[4];

  auto relload = [&](bool isA, int kt, unsigned int* dst){
    int off = kt * 64 + 4 * l4;
    if (U8){
      const u8* p = isA ? r8A : r8B;
#pragma unroll
      for (int t = 0; t < 4; ++t) dst[t] = *(const unsigned int*)(p + off + 16 * t);
    } else {
      const int* p = isA ? r32A : r32B;
#pragma unroll
      for (int t = 0; t < 4; ++t){
        int4 v4 = *(const int4*)(p + off + 16 * t);
        dst[t] = (unsigned int)(v4.x & 255) | ((unsigned int)(v4.y & 255) << 8)
               | ((unsigned int)(v4.z & 255) << 16) | ((unsigned int)(v4.w & 255) << 24);
      }
    }
  };

  auto writeout = [&](int Td, int q0){
    asm volatile("s_nop 7\n\ts_nop 7" :::);
    float s = rsum;
    s += __shfl_xor(s, 16);
    s += __shfl_xor(s, 32);
    float invZ = 1.f / (s + (float)(2048 - (Td + 1) * 64));
    int qg = q0 + w * 16 + l15;
    const float* sufp = vsuf + ((size_t)bh * 33 + Td + 1) * 64;
#pragma unroll
    for (int ni = 0; ni < 4; ++ni){
      float4 sv = *(const float4*)(sufp + ni * 16 + 4 * l4);
      unsigned int lo = (unsigned int)f2bf((acc[ni][0] + sv.x) * invZ)
                      | ((unsigned int)f2bf((acc[ni][1] + sv.y) * invZ) << 16);
      unsigned int hi = (unsigned int)f2bf((acc[ni][2] + sv.z) * invZ)
                      | ((unsigned int)f2bf((acc[ni][3] + sv.w) * invZ) << 16);
      uint2 o; o.x = lo; o.y = hi;
      *(uint2*)(ab + ((size_t)b * 2048 + qg) * 1024 + h * 64 + ni * 16 + 4 * l4) = o;
    }
  };

  const int lo = g ? 17 : 0;
  const int hi = g ? 33 : 17;

  {
    bool isA0 = (lo <= TA);
    int kt0 = isA0 ? lo : lo - TA - 1;
    STAGE(kt0, 0);
    relload(isA0, kt0, relc);
  }
  __syncthreads();

  for (int it = lo; it < hi; ++it){
    const bool isA = (it <= TA);
    const int kt = isA ? it : (it - TA - 1);
    const int cur = (it - lo) & 1;

    if (it + 1 < hi){
      const bool nA = (it + 1 <= TA);
      const int nkt = nA ? (it + 1) : (it - TA);
      STAGE(nkt, cur ^ 1);
      relload(nA, nkt, reln);
    }

    const short8 a0 = isA ? aqA0 : aqB0;
    const short8 a1 = isA ? aqA1 : aqB1;
    const bool diag = (kt == (isA ? TA : TB));

    short4v pk[4];
    __builtin_amdgcn_s_setprio(1);
#pragma unroll
    for (int t = 0; t < 4; ++t){
      const int krow = 16 * t + l15;
      const u16* kbase = &Kt[g][cur][krow * 64];
      short8 bk0 = *(const short8*)&kbase[((l4)     ^ (krow & 7)) * 8];
      short8 bk1 = *(const short8*)&kbase[((4 + l4) ^ (krow & 7)) * 8];
      f32x4 sf = {0.f, 0.f, 0.f, 0.f};
      sf = __builtin_amdgcn_mfma_f32_16x16x32_bf16(bk0, a0, sf, 0, 0, 0);
      sf = __builtin_amdgcn_mfma_f32_16x16x32_bf16(bk1, a1, sf, 0, 0, 0);
      unsigned int rw = relc[t];
      const int kk = 16 * t + 4 * l4;
#pragma unroll
      for (int r = 0; r < 4; ++r){
        float sc = sf[r] * remb[(rw >> (8 * r)) & 255];
        if (diag) sc = (kk + r <= w * 16 + l15) ? sc : 0.f;
        float p = __builtin_amdgcn_exp2f(sc);
        rsum += p;
        pk[t][r] = (short)f2bf(p);
      }
    }
    asm volatile("s_nop 2" :::);
#pragma unroll
    for (int ni = 0; ni < 4; ++ni){
      const int drow = ni * 16 + l15;
      const u16* vbase = &Vt[g][cur][drow * 64];
      short8 vv0 = *(const short8*)&vbase[(((2 * l4)     ^ (drow & 7))) * 8];
      short8 vv1 = *(const short8*)&vbase[(((2 * l4 + 1) ^ (drow & 7))) * 8];
      short4v va0 = {vv0[0], vv0[1], vv0[2], vv0[3]};
      short4v va1 = {vv0[4], vv0[5], vv0[6], vv0[7]};
      short4v va2 = {vv1[0], vv1[1], vv1[2], vv1[3]};
      short4v va3 = {vv1[4], vv1[5], vv1[6], vv1[7]};
      acc[ni] = mfma16(va0, pk[0], acc[ni]);
      acc[ni] = mfma16(va1, pk[1], acc[ni]);
      acc[ni] = mfma16(va2, pk[2], acc[ni]);
      acc[ni] = mfma16(va3, pk[3], acc[ni]);
    }
    __builtin_amdgcn_s_setprio(0);

    if (it == TA){   // boundary crossing (isA here by construction)
      if (g == 0){
        writeout(TA, q0A);           // A complete within group 0
      } else {
#pragma unroll
        for (int ni = 0; ni < 4; ++ni) accS[ni] = acc[ni];
        rsumS = rsum;
      }
#pragma unroll
      for (int ni = 0; ni < 4; ++ni) acc[ni] = f32x4{0.f, 0.f, 0.f, 0.f};
      rsum = 0.f;
    }
    if (it + 1 < hi){
#pragma unroll
      for (int t = 0; t < 4; ++t) relc[t] = reln[t];
    }
    __syncthreads();
  }
#undef STAGE
  if (g) __syncthreads();   // equalize barrier count (g0: 17 loop iters, g1: 16)

  const bool Ble = (TA <= 16);        // split tile: B (donor g0, writer g1) else A (donor g1, writer g0)
  if (!Ble && g == 1) writeout(TB, q0B);   // g1 holds complete B when TA>=17

  float* scr = (float*)&Kt[0][0][0];  // 64 x 68-stride f32, aliases dead K buffers
  if (Ble ? (g == 0) : (g == 1)){
#pragma unroll
    for (int ni = 0; ni < 4; ++ni){
      f32x4 src = Ble ? acc[ni] : accS[ni];
      *(f32x4*)&scr[(w * 16 + l15) * 68 + ni * 16 + 4 * l4] = src;
    }
    scrsum[w][lane] = Ble ? rsum : rsumS;
  }
  __syncthreads();
  if (Ble ? (g == 1) : (g == 0)){
#pragma unroll
    for (int ni = 0; ni < 4; ++ni){
      f32x4 d = *(const f32x4*)&scr[(w * 16 + l15) * 68 + ni * 16 + 4 * l4];
      acc[ni][0] += d[0]; acc[ni][1] += d[1]; acc[ni][2] += d[2]; acc[ni][3] += d[3];
    }
    rsum += scrsum[w][lane];
    if (Ble) writeout(TB, q0B);
    else     writeout(TA, q0A);
  }
}

// ---------------- launch ----------------
extern "C" void kernel_launch(void* const* d_in, const int* in_sizes, int n_in,
                              void* d_out, int out_size, void* d_ws, size_t ws_size,
                              hipStream_t stream){
  const float* x       = (const float*)d_in[0];
  const float* Wqkv    = (const float*)d_in[1];
  const float* bqkv    = (const float*)d_in[2];
  const float* Wproj   = (const float*)d_in[3];
  const float* bproj   = (const float*)d_in[4];
  const float* rel_emb = (const float*)d_in[5];
  const int*   rel     = (const int*)d_in[6];
  float* out = (float*)d_out;

  char* ws = (char*)d_ws;
  u16* xb     = (u16*)(ws);                      // 8 MB (x bf16; later reused as attn output)
  u16* wqkvT  = (u16*)(ws + (8ull  << 20));      // 6 MB
  u16* wprojT = (u16*)(ws + (14ull << 20));      // 2 MB
  u16* qb     = (u16*)(ws + (16ull << 20));      // 8 MB
  u16* kb     = (u16*)(ws + (24ull << 20));      // 8 MB
  u16* vb     = (u16*)(ws + (32ull << 20));      // 8 MB
  u16* vtb    = (u16*)(ws + (40ull << 20));      // 8 MB
  float* vsuf = (float*)(ws + (48ull << 20));    // 270 KB
  float* vpart= (float*)(ws + (48ull << 20) + (512ull << 10)); // 256 KB
  u8*   rel8  = (u8*)(ws + (49ull << 20));       // 8.4 MB (only if ws allows)
  const bool useU8 = ws_size >= (58ull << 20);

  cvt_k<<<4096, 256, 0, stream>>>(x, xb, 1048576);
  tconv_k<<<dim3(96, 32), dim3(32, 8), 0, stream>>>(Wqkv, wqkvT, 1024, 3072);
  tconv_k<<<dim3(32, 32), dim3(32, 8), 0, stream>>>(Wproj, wprojT, 1024, 1024);
  if (useU8) rel8_k<<<8192, 256, 0, stream>>>(rel, rel8, 2097152);
  gemm_bt_k<128, 0><<<dim3(24, 32), 256, 0, stream>>>(xb, wqkvT, bqkv, qb, kb, vb, nullptr, 4096, 3072, 1024);
  transpose_v_k<<<1024, 256, 0, stream>>>(vb, vtb, vpart);
  vsufscan_k<<<32, 64, 0, stream>>>(vpart, vsuf);
  if (useU8)
    attn_k<1><<<dim3(16, 32), 512, 0, stream>>>(qb, kb, vtb, vsuf, rel8, rel_emb, xb);
  else
    attn_k<0><<<dim3(16, 32), 512, 0, stream>>>(qb, kb, vtb, vsuf, rel, rel_emb, xb);
  gemm_bt_k<64, 1><<<dim3(16, 32), 256, 0, stream>>>(xb, wprojT, bproj, nullptr, nullptr, nullptr, out, 4096, 1024, 1024);
}

// Round 6
// 154.930 us; speedup vs baseline: 1.2343x; 1.2343x over previous
//
#include <hip/hip_runtime.h>

typedef unsigned short u16;
typedef unsigned char u8;
typedef __attribute__((ext_vector_type(8))) short short8;
typedef __attribute__((ext_vector_type(4))) short short4v;
typedef __attribute__((ext_vector_type(4))) float f32x4;

#define GLD16(g, l) __builtin_amdgcn_global_load_lds( \
    (const __attribute__((address_space(1))) void*)(g), \
    (__attribute__((address_space(3))) void*)(l), 16, 0, 0)

__device__ __forceinline__ float bf2f(u16 u){
  union { unsigned int i; float f; } v; v.i = ((unsigned int)u) << 16; return v.f;
}
__device__ __forceinline__ u16 f2bf(float f){
  union { float f; unsigned int i; } v; v.f = f;
  unsigned int u = v.i;
  unsigned int r = (u + 0x7FFFu + ((u >> 16) & 1u)) >> 16;
  return (u16)r;
}

__device__ __forceinline__ f32x4 mfma16(short4v a, short4v b, f32x4 c){
#if __has_builtin(__builtin_amdgcn_mfma_f32_16x16x16bf16_1k)
  return __builtin_amdgcn_mfma_f32_16x16x16bf16_1k(a, b, c, 0, 0, 0);
#else
  asm volatile("s_nop 1\n\tv_mfma_f32_16x16x16_bf16 %0, %1, %2, %0" : "+v"(c) : "v"(a), "v"(b));
  return c;
#endif
}

// ---------------- elementwise fp32 -> bf16 (x) ----------------
__global__ void cvt_k(const float* __restrict__ x, u16* __restrict__ o, int n4){
  int i = blockIdx.x * 256 + threadIdx.x;
  if (i >= n4) return;
  float4 v = ((const float4*)x)[i];
  unsigned long long pk = (unsigned long long)f2bf(v.x)
    | ((unsigned long long)f2bf(v.y) << 16)
    | ((unsigned long long)f2bf(v.z) << 32)
    | ((unsigned long long)f2bf(v.w) << 48);
  ((unsigned long long*)o)[i] = pk;
}

// ---------------- rel int32 -> u8 ----------------
__global__ void rel8_k(const int* __restrict__ r, u8* __restrict__ o, int n4){
  int i = blockIdx.x * 256 + threadIdx.x;
  if (i >= n4) return;
  int4 v = ((const int4*)r)[i];
  unsigned int pk = (unsigned int)(v.x & 255) | ((unsigned int)(v.y & 255) << 8)
    | ((unsigned int)(v.z & 255) << 16) | ((unsigned int)(v.w & 255) << 24);
  ((unsigned int*)o)[i] = pk;
}

// ---------------- transpose + convert weights: W[K,N] f32 -> Wt[N,K] bf16 ----------------
__global__ void tconv_k(const float* __restrict__ W, u16* __restrict__ Wt, int K, int N){
  __shared__ float tl[32][33];
  int n0 = blockIdx.x * 32, k0 = blockIdx.y * 32;
  for (int i = threadIdx.y; i < 32; i += 8)
    tl[i][threadIdx.x] = W[(size_t)(k0 + i) * N + n0 + threadIdx.x];
  __syncthreads();
  for (int i = threadIdx.y; i < 32; i += 8)
    Wt[(size_t)(n0 + i) * K + k0 + threadIdx.x] = f2bf(tl[threadIdx.x][i]);
}

// ---------------- bf16 GEMM (B^T input), BK=64, XOR-swizzled LDS ----------------
template<int BN, int MODE>
__global__ __launch_bounds__(256) void gemm_bt_k(const u16* __restrict__ A, const u16* __restrict__ Bt,
                                                 const float* __restrict__ bias,
                                                 u16* __restrict__ oq, u16* __restrict__ okk, u16* __restrict__ ov,
                                                 float* __restrict__ of,
                                                 int M, int N, int K){
  __shared__ u16 la[128 * 64];
  __shared__ u16 lb[BN * 64];
  const int t = threadIdx.x, w = t >> 6, lane = t & 63;
  const int l15 = lane & 15, l4 = lane >> 4;
  const int m0 = blockIdx.y * 128, n0 = blockIdx.x * BN;
  const int wr = w >> 1, wc = w & 1;
  constexpr int NI = BN / 32;
  f32x4 acc[4][NI] = {};
  const u16* Abase = A + (size_t)m0 * K;
  const u16* Bbase = Bt + (size_t)n0 * K;
  for (int kt = 0; kt < K; kt += 64){
    __syncthreads();
#pragma unroll
    for (int i = 0; i < 4; ++i){
      int chunk = i * 256 + t;
      int row = chunk >> 3, cs = chunk & 7;
      int c = cs ^ (row & 7);
      GLD16(Abase + (size_t)row * K + kt + c * 8, &la[(i * 256 + w * 64) * 8]);
    }
#pragma unroll
    for (int i = 0; i < BN / 32; ++i){
      int chunk = i * 256 + t;
      int row = chunk >> 3, cs = chunk & 7;
      int c = cs ^ (row & 7);
      GLD16(Bbase + (size_t)row * K + kt + c * 8, &lb[(i * 256 + w * 64) * 8]);
    }
    asm volatile("s_waitcnt vmcnt(0)" ::: "memory");
    __syncthreads();
    short8 af[4][2], bfr[NI][2];
#pragma unroll
    for (int mi = 0; mi < 4; ++mi){
      int row = wr * 64 + mi * 16 + l15;
#pragma unroll
      for (int h = 0; h < 2; ++h)
        af[mi][h] = *(const short8*)&la[row * 64 + (((h * 4 + l4) ^ (row & 7)) * 8)];
    }
#pragma unroll
    for (int ni = 0; ni < NI; ++ni){
      int row = wc * (BN / 2) + ni * 16 + l15;
#pragma unroll
      for (int h = 0; h < 2; ++h)
        bfr[ni][h] = *(const short8*)&lb[row * 64 + (((h * 4 + l4) ^ (row & 7)) * 8)];
    }
#pragma unroll
    for (int mi = 0; mi < 4; ++mi)
#pragma unroll
      for (int ni = 0; ni < NI; ++ni){
        acc[mi][ni] = __builtin_amdgcn_mfma_f32_16x16x32_bf16(af[mi][0], bfr[ni][0], acc[mi][ni], 0, 0, 0);
        acc[mi][ni] = __builtin_amdgcn_mfma_f32_16x16x32_bf16(af[mi][1], bfr[ni][1], acc[mi][ni], 0, 0, 0);
      }
  }
#pragma unroll
  for (int mi = 0; mi < 4; ++mi){
#pragma unroll
    for (int ni = 0; ni < NI; ++ni){
#pragma unroll
      for (int r = 0; r < 4; ++r){
        int m = m0 + wr * 64 + mi * 16 + l4 * 4 + r;
        int n = n0 + wc * (BN / 2) + ni * 16 + l15;
        float v = acc[mi][ni][r] + bias[n];
        if (MODE == 0){
          int tt = n >> 10, rr = n & 1023, head = rr >> 6, d = rr & 63;
          int b = m >> 11, s = m & 2047;
          u16* dst = (tt == 0) ? oq : (tt == 1) ? okk : ov;
          dst[(((size_t)(b * 16 + head)) * 2048 + s) * 64 + d] = f2bf(v);
        } else {
          of[(size_t)m * N + n] = v;
        }
      }
    }
  }
}

// ---------------- V transpose (k-field-permuted) + per-chunk column sums ----------------
__global__ __launch_bounds__(256) void transpose_v_k(const u16* __restrict__ vb, u16* __restrict__ vt,
                                                     float* __restrict__ vpart){
  __shared__ u16 tl[64][65];
  int bh = blockIdx.x >> 5, c = blockIdx.x & 31, s0 = c * 64;
  int t = threadIdx.x;
#pragma unroll
  for (int rsub = 0; rsub < 16; ++rsub){
    int idx = rsub * 256 + t;
    int i = idx >> 6, d = idx & 63;
    tl[i][d] = vb[(((size_t)bh * 2048) + s0 + i) * 64 + d];
  }
  __syncthreads();
#pragma unroll
  for (int rsub = 0; rsub < 16; ++rsub){
    int idx = rsub * 256 + t;
    int d = idx >> 6, j = idx & 63;
    int pj = (j & 3) | (((j >> 2) & 3) << 4) | (((j >> 4) & 3) << 2);
    vt[(((size_t)bh * 64) + d) * 2048 + s0 + pj] = tl[j][d];
  }
  if (t < 64){
    float s = 0.f;
#pragma unroll 8
    for (int j = 0; j < 64; ++j) s += bf2f(tl[j][t]);
    vpart[((size_t)bh * 32 + c) * 64 + t] = s;
  }
}

// ---------------- suffix scan over V chunk sums ----------------
__global__ void vsufscan_k(const float* __restrict__ vpart, float* __restrict__ vsuf){
  int bh = blockIdx.x, d = threadIdx.x;   // 64 threads
  float run = 0.f;
  vsuf[((size_t)bh * 33 + 32) * 64 + d] = 0.f;
  for (int c = 31; c >= 0; --c){
    run += vpart[((size_t)bh * 32 + c) * 64 + d];
    vsuf[((size_t)bh * 33 + c) * 64 + d] = run;
  }
}

// ---------------- fused rel-bias causal attention (swapped-operand, cross-block split) ----------------
// SPLIT=1: grid (32,32), block (p=bx>>1, h=bx&1): TA=p in [0,16), TB=31-p.
//   h=0 runs virtual iters [0,17): ALL of A (writes ab directly) + B k-tiles 0..15-p.
//   h=1 runs [17,33): B k-tiles 16-p..TB. Both emit unnormalized B partials
//   (f32 acc + rsum) to slot h; fixed m=0 makes combine a pure add (attn_fin_k).
// SPLIT=0: grid (16,32), R4-equivalent single-block pair.
template<int U8, int SPLIT>
__global__ __launch_bounds__(256, 4) void attn_k(const u16* __restrict__ qb, const u16* __restrict__ kb,
                                                 const u16* __restrict__ vt, const float* __restrict__ vsuf,
                                                 const void* __restrict__ relp, const float* __restrict__ rel_emb,
                                                 u16* __restrict__ ab, float* __restrict__ pacc,
                                                 float* __restrict__ prsum){
  __shared__ u16 Kt[2][64 * 64];
  __shared__ u16 Vt[2][64 * 64];
  __shared__ float remb[64];
  const int bx = blockIdx.x, bh = blockIdx.y;
  const int p = SPLIT ? (bx >> 1) : bx;
  const int hf = SPLIT ? (bx & 1) : 0;
  const int b = bh >> 4, h = bh & 15;
  const int TA = p, TB = 31 - p;
  const int q0A = TA * 64, q0B = TB * 64;
  const int tid = threadIdx.x, w = tid >> 6, lane = tid & 63;
  const int l15 = lane & 15, l4 = lane >> 4;
  if (tid < 64) remb[tid] = rel_emb[tid * 16 + h] * (0.125f * 1.44269504088896f);
  const u16* kbh = kb + ((size_t)bh * 2048) * 64;
  const u16* vbh = vt + ((size_t)bh * 64) * 2048;
  const u16* qA = qb + (((size_t)bh * 2048) + q0A + w * 16 + l15) * 64 + l4 * 8;
  const u16* qB = qb + (((size_t)bh * 2048) + q0B + w * 16 + l15) * 64 + l4 * 8;
  const short8 aqA0 = *(const short8*)qA, aqA1 = *(const short8*)(qA + 32);
  const short8 aqB0 = *(const short8*)qB, aqB1 = *(const short8*)(qB + 32);
  const u8*  r8A  = (const u8*)relp + ((size_t)b * 2048 + q0A + w * 16 + l15) * 2048;
  const u8*  r8B  = (const u8*)relp + ((size_t)b * 2048 + q0B + w * 16 + l15) * 2048;
  const int* r32A = (const int*)relp + ((size_t)b * 2048 + q0A + w * 16 + l15) * 2048;
  const int* r32B = (const int*)relp + ((size_t)b * 2048 + q0B + w * 16 + l15) * 2048;

  const int srow0 = (tid >> 3), srow1 = 32 + (tid >> 3);
  const int scs = tid & 7;
  const int sc0 = scs ^ (srow0 & 7), sc1 = scs ^ (srow1 & 7);
  const int sldsoff = (w * 64) * 8;

#define STAGE(ktile, buf) do {                                                       \
    GLD16(kbh + (size_t)((ktile) * 64 + srow0) * 64 + sc0 * 8, &Kt[buf][sldsoff]);   \
    GLD16(kbh + (size_t)((ktile) * 64 + srow1) * 64 + sc1 * 8, &Kt[buf][2048 + sldsoff]); \
    GLD16(vbh + (size_t)srow0 * 2048 + (ktile) * 64 + sc0 * 8, &Vt[buf][sldsoff]);   \
    GLD16(vbh + (size_t)srow1 * 2048 + (ktile) * 64 + sc1 * 8, &Vt[buf][2048 + sldsoff]); \
  } while (0)

  f32x4 acc[4] = {};
  float rsum = 0.f;
  unsigned int relc[4], reln[4];

  auto relload = [&](bool isA, int kt, unsigned int* dst){
    int off = kt * 64 + 4 * l4;
    if (U8){
      const u8* pp = isA ? r8A : r8B;
#pragma unroll
      for (int t = 0; t < 4; ++t) dst[t] = *(const unsigned int*)(pp + off + 16 * t);
    } else {
      const int* pp = isA ? r32A : r32B;
#pragma unroll
      for (int t = 0; t < 4; ++t){
        int4 v4 = *(const int4*)(pp + off + 16 * t);
        dst[t] = (unsigned int)(v4.x & 255) | ((unsigned int)(v4.y & 255) << 8)
               | ((unsigned int)(v4.z & 255) << 16) | ((unsigned int)(v4.w & 255) << 24);
      }
    }
  };

  auto writeout = [&](int Td, int q0){
    asm volatile("s_nop 7\n\ts_nop 7" :::);
    float s = rsum;
    s += __shfl_xor(s, 16);
    s += __shfl_xor(s, 32);
    float invZ = 1.f / (s + (float)(2048 - (Td + 1) * 64));
    int qg = q0 + w * 16 + l15;
    const float* sufp = vsuf + ((size_t)bh * 33 + Td + 1) * 64;
#pragma unroll
    for (int ni = 0; ni < 4; ++ni){
      float4 sv = *(const float4*)(sufp + ni * 16 + 4 * l4);
      unsigned int lo2 = (unsigned int)f2bf((acc[ni][0] + sv.x) * invZ)
                       | ((unsigned int)f2bf((acc[ni][1] + sv.y) * invZ) << 16);
      unsigned int hi2 = (unsigned int)f2bf((acc[ni][2] + sv.z) * invZ)
                       | ((unsigned int)f2bf((acc[ni][3] + sv.w) * invZ) << 16);
      uint2 o; o.x = lo2; o.y = hi2;
      *(uint2*)(ab + ((size_t)b * 2048 + qg) * 1024 + h * 64 + ni * 16 + 4 * l4) = o;
    }
  };

  const int lo = (SPLIT && hf) ? 17 : 0;
  const int hi = (SPLIT && !hf) ? 17 : 33;

  {
    bool isA0 = (lo <= TA);
    int kt0 = isA0 ? lo : lo - TA - 1;
    STAGE(kt0, 0);
    relload(isA0, kt0, relc);
  }
  __syncthreads();

  for (int it = lo; it < hi; ++it){
    const bool isA = (it <= TA);
    const int kt = isA ? it : (it - TA - 1);
    const int cur = (it - lo) & 1;

    if (it + 1 < hi){
      const bool nA = (it + 1 <= TA);
      const int nkt = nA ? (it + 1) : (it - TA);
      STAGE(nkt, cur ^ 1);
      relload(nA, nkt, reln);
    }

    const short8 a0 = isA ? aqA0 : aqB0;
    const short8 a1 = isA ? aqA1 : aqB1;
    const bool diag = (kt == (isA ? TA : TB));

    short4v pk[4];
    __builtin_amdgcn_s_setprio(1);
#pragma unroll
    for (int t = 0; t < 4; ++t){
      const int krow = 16 * t + l15;
      const u16* kbase = &Kt[cur][krow * 64];
      short8 bk0 = *(const short8*)&kbase[((l4)     ^ (krow & 7)) * 8];
      short8 bk1 = *(const short8*)&kbase[((4 + l4) ^ (krow & 7)) * 8];
      f32x4 sf = {0.f, 0.f, 0.f, 0.f};
      sf = __builtin_amdgcn_mfma_f32_16x16x32_bf16(bk0, a0, sf, 0, 0, 0);
      sf = __builtin_amdgcn_mfma_f32_16x16x32_bf16(bk1, a1, sf, 0, 0, 0);
      unsigned int rw = relc[t];
      const int kk = 16 * t + 4 * l4;
#pragma unroll
      for (int r = 0; r < 4; ++r){
        float sc = sf[r] * remb[(rw >> (8 * r)) & 255];
        if (diag) sc = (kk + r <= w * 16 + l15) ? sc : 0.f;
        float pv = __builtin_amdgcn_exp2f(sc);
        rsum += pv;
        pk[t][r] = (short)f2bf(pv);
      }
    }
    asm volatile("s_nop 2" :::);
#pragma unroll
    for (int ni = 0; ni < 4; ++ni){
      const int drow = ni * 16 + l15;
      const u16* vbase = &Vt[cur][drow * 64];
      short8 vv0 = *(const short8*)&vbase[(((2 * l4)     ^ (drow & 7))) * 8];
      short8 vv1 = *(const short8*)&vbase[(((2 * l4 + 1) ^ (drow & 7))) * 8];
      short4v va0 = {vv0[0], vv0[1], vv0[2], vv0[3]};
      short4v va1 = {vv0[4], vv0[5], vv0[6], vv0[7]};
      short4v va2 = {vv1[0], vv1[1], vv1[2], vv1[3]};
      short4v va3 = {vv1[4], vv1[5], vv1[6], vv1[7]};
      acc[ni] = mfma16(va0, pk[0], acc[ni]);
      acc[ni] = mfma16(va1, pk[1], acc[ni]);
      acc[ni] = mfma16(va2, pk[2], acc[ni]);
      acc[ni] = mfma16(va3, pk[3], acc[ni]);
    }
    __builtin_amdgcn_s_setprio(0);

    if (it == TA){   // A complete (only reachable when hf==0)
      writeout(TA, q0A);
#pragma unroll
      for (int ni = 0; ni < 4; ++ni) acc[ni] = f32x4{0.f, 0.f, 0.f, 0.f};
      rsum = 0.f;
    }
    if (it + 1 < hi){
#pragma unroll
      for (int t = 0; t < 4; ++t) relc[t] = reln[t];
    }
    __syncthreads();
  }
#undef STAGE

  if (SPLIT){
    // emit unnormalized B partial to slot hf
    asm volatile("s_nop 7\n\ts_nop 7" :::);
    float s = rsum;
    s += __shfl_xor(s, 16);
    s += __shfl_xor(s, 32);
    const size_t slot = (((size_t)bh * 16 + p) * 2 + hf);
    float* pslot = pacc + slot * 4096;
#pragma unroll
    for (int ni = 0; ni < 4; ++ni)
      *(f32x4*)(pslot + (w * 16 + l15) * 64 + ni * 16 + 4 * l4) = acc[ni];
    if (l4 == 0) prsum[slot * 64 + w * 16 + l15] = s;
  } else {
    writeout(TB, q0B);
  }
}

// ---------------- combine B partials + suffix + normalize + store ----------------
__global__ __launch_bounds__(256) void attn_fin_k(const float* __restrict__ pacc,
                                                  const float* __restrict__ prsum,
                                                  const float* __restrict__ vsuf,
                                                  u16* __restrict__ ab){
  const int p = blockIdx.x, bh = blockIdx.y;
  const int b = bh >> 4, h = bh & 15;
  const int TB = 31 - p, q0 = TB * 64;
  const int r = threadIdx.x >> 2, cg = threadIdx.x & 3;
  const size_t slot = ((size_t)bh * 16 + p) * 2;
  const size_t base = slot * 4096 + r * 64 + cg * 16;
  float rs = prsum[slot * 64 + r] + prsum[(slot + 1) * 64 + r];
  float invZ = 1.f / (rs + (float)(2048 - (TB + 1) * 64));
  const float* sufp = vsuf + ((size_t)bh * 33 + TB + 1) * 64 + cg * 16;
  u16 o[16];
#pragma unroll
  for (int j = 0; j < 4; ++j){
    f32x4 a0 = *(const f32x4*)(pacc + base + j * 4);
    f32x4 a1 = *(const f32x4*)(pacc + base + 4096 + j * 4);
    f32x4 sv = *(const f32x4*)(sufp + j * 4);
#pragma unroll
    for (int e = 0; e < 4; ++e) o[j * 4 + e] = f2bf((a0[e] + a1[e] + sv[e]) * invZ);
  }
  u16* dst = ab + ((size_t)b * 2048 + q0 + r) * 1024 + h * 64 + cg * 16;
  *(uint4*)dst = *(const uint4*)&o[0];
  *(uint4*)(dst + 8) = *(const uint4*)&o[8];
}

// ---------------- launch ----------------
extern "C" void kernel_launch(void* const* d_in, const int* in_sizes, int n_in,
                              void* d_out, int out_size, void* d_ws, size_t ws_size,
                              hipStream_t stream){
  const float* x       = (const float*)d_in[0];
  const float* Wqkv    = (const float*)d_in[1];
  const float* bqkv    = (const float*)d_in[2];
  const float* Wproj   = (const float*)d_in[3];
  const float* bproj   = (const float*)d_in[4];
  const float* rel_emb = (const float*)d_in[5];
  const int*   rel     = (const int*)d_in[6];
  float* out = (float*)d_out;

  char* ws = (char*)d_ws;
  u16* xb     = (u16*)(ws);                      // 8 MB (x bf16; later attn output)
  u16* wqkvT  = (u16*)(ws + (8ull  << 20));      // 6 MB
  u16* wprojT = (u16*)(ws + (14ull << 20));      // 2 MB
  u16* qb     = (u16*)(ws + (16ull << 20));      // 8 MB
  u16* kb     = (u16*)(ws + (24ull << 20));      // 8 MB
  u16* vb     = (u16*)(ws + (32ull << 20));      // 8 MB
  u16* vtb    = (u16*)(ws + (40ull << 20));      // 8 MB
  float* vsuf = (float*)(ws + (48ull << 20));                   // 270 KB
  float* vpart= (float*)(ws + (48ull << 20) + (512ull << 10));  // 256 KB
  float* pacc = (float*)(ws + (49ull << 20));    // 16 MB (B partials, SPLIT only)
  float* prsum= (float*)(ws + (65ull << 20) + (512ull << 10));  // 256 KB
  u8*   rel8  = (u8*)(ws + (66ull << 20));       // 8.4 MB
  const bool useSplit = ws_size >= (67ull << 20);
  const bool useU8    = ws_size >= (75ull << 20);

  cvt_k<<<4096, 256, 0, stream>>>(x, xb, 1048576);
  tconv_k<<<dim3(96, 32), dim3(32, 8), 0, stream>>>(Wqkv, wqkvT, 1024, 3072);
  tconv_k<<<dim3(32, 32), dim3(32, 8), 0, stream>>>(Wproj, wprojT, 1024, 1024);
  if (useU8) rel8_k<<<8192, 256, 0, stream>>>(rel, rel8, 2097152);
  gemm_bt_k<128, 0><<<dim3(24, 32), 256, 0, stream>>>(xb, wqkvT, bqkv, qb, kb, vb, nullptr, 4096, 3072, 1024);
  transpose_v_k<<<1024, 256, 0, stream>>>(vb, vtb, vpart);
  vsufscan_k<<<32, 64, 0, stream>>>(vpart, vsuf);
  if (useU8)
    attn_k<1, 1><<<dim3(32, 32), 256, 0, stream>>>(qb, kb, vtb, vsuf, rel8, rel_emb, xb, pacc, prsum);
  else if (useSplit)
    attn_k<0, 1><<<dim3(32, 32), 256, 0, stream>>>(qb, kb, vtb, vsuf, rel, rel_emb, xb, pacc, prsum);
  else
    attn_k<0, 0><<<dim3(16, 32), 256, 0, stream>>>(qb, kb, vtb, vsuf, rel, rel_emb, xb, pacc, prsum);
  if (useSplit || useU8)
    attn_fin_k<<<dim3(16, 32), 256, 0, stream>>>(pacc, prsum, vsuf, xb);
  gemm_bt_k<64, 1><<<dim3(16, 32), 256, 0, stream>>>(xb, wprojT, bproj, nullptr, nullptr, nullptr, out, 4096, 1024, 1024);
}

// Round 7
// 146.563 us; speedup vs baseline: 1.3047x; 1.0571x over previous
//
#include <hip/hip_runtime.h>

typedef unsigned short u16;
typedef unsigned char u8;
typedef __attribute__((ext_vector_type(8))) short short8;
typedef __attribute__((ext_vector_type(4))) short short4v;
typedef __attribute__((ext_vector_type(4))) float f32x4;

#define GLD16(g, l) __builtin_amdgcn_global_load_lds( \
    (const __attribute__((address_space(1))) void*)(g), \
    (__attribute__((address_space(3))) void*)(l), 16, 0, 0)

__device__ __forceinline__ float bf2f(u16 u){
  union { unsigned int i; float f; } v; v.i = ((unsigned int)u) << 16; return v.f;
}
__device__ __forceinline__ u16 f2bf(float f){
  union { float f; unsigned int i; } v; v.f = f;
  unsigned int u = v.i;
  unsigned int r = (u + 0x7FFFu + ((u >> 16) & 1u)) >> 16;
  return (u16)r;
}

__device__ __forceinline__ f32x4 mfma16(short4v a, short4v b, f32x4 c){
#if __has_builtin(__builtin_amdgcn_mfma_f32_16x16x16bf16_1k)
  return __builtin_amdgcn_mfma_f32_16x16x16bf16_1k(a, b, c, 0, 0, 0);
#else
  asm volatile("s_nop 1\n\tv_mfma_f32_16x16x16_bf16 %0, %1, %2, %0" : "+v"(c) : "v"(a), "v"(b));
  return c;
#endif
}

// ---------------- fused prep: x->bf16 | Wqkv^T | Wproj^T | rel->u8 ----------------
// roles by blockIdx.x range: [0,4096) cvt, [4096,7168) tconv qkv,
// [7168,8192) tconv proj, [8192,16384) rel8 (only when useU8).
__global__ __launch_bounds__(256) void prep_k(const float* __restrict__ x, u16* __restrict__ xb,
                                              const float* __restrict__ Wqkv, u16* __restrict__ wqkvT,
                                              const float* __restrict__ Wproj, u16* __restrict__ wprojT,
                                              const int* __restrict__ rel, u8* __restrict__ rel8){
  const int bid = blockIdx.x, t = threadIdx.x;
  if (bid < 4096){
    int i = bid * 256 + t;
    float4 v = ((const float4*)x)[i];
    unsigned long long pk = (unsigned long long)f2bf(v.x)
      | ((unsigned long long)f2bf(v.y) << 16)
      | ((unsigned long long)f2bf(v.z) << 32)
      | ((unsigned long long)f2bf(v.w) << 48);
    ((unsigned long long*)xb)[i] = pk;
  } else if (bid < 8192){
    const float* W; u16* Wt; int K, N, blk, nbx;
    if (bid < 7168){ W = Wqkv; Wt = wqkvT; K = 1024; N = 3072; blk = bid - 4096; nbx = 96; }
    else           { W = Wproj; Wt = wprojT; K = 1024; N = 1024; blk = bid - 7168; nbx = 32; }
    __shared__ float tl[32][33];
    int n0 = (blk % nbx) * 32, k0 = (blk / nbx) * 32;
    int tx = t & 31, ty = t >> 5;
    for (int i = ty; i < 32; i += 8)
      tl[i][tx] = W[(size_t)(k0 + i) * N + n0 + tx];
    __syncthreads();
    for (int i = ty; i < 32; i += 8)
      Wt[(size_t)(n0 + i) * K + k0 + tx] = f2bf(tl[tx][i]);
  } else {
    int i = (bid - 8192) * 256 + t;
    int4 v = ((const int4*)rel)[i];
    unsigned int pk = (unsigned int)(v.x & 255) | ((unsigned int)(v.y & 255) << 8)
      | ((unsigned int)(v.z & 255) << 16) | ((unsigned int)(v.w & 255) << 24);
    ((unsigned int*)rel8)[i] = pk;
  }
}

// ---------------- bf16 GEMM (B^T input), BK=64, XOR-swizzled LDS ----------------
template<int BN, int MODE>
__global__ __launch_bounds__(256) void gemm_bt_k(const u16* __restrict__ A, const u16* __restrict__ Bt,
                                                 const float* __restrict__ bias,
                                                 u16* __restrict__ oq, u16* __restrict__ okk, u16* __restrict__ ov,
                                                 float* __restrict__ of,
                                                 int M, int N, int K){
  __shared__ u16 la[128 * 64];
  __shared__ u16 lb[BN * 64];
  const int t = threadIdx.x, w = t >> 6, lane = t & 63;
  const int l15 = lane & 15, l4 = lane >> 4;
  const int m0 = blockIdx.y * 128, n0 = blockIdx.x * BN;
  const int wr = w >> 1, wc = w & 1;
  constexpr int NI = BN / 32;
  f32x4 acc[4][NI] = {};
  const u16* Abase = A + (size_t)m0 * K;
  const u16* Bbase = Bt + (size_t)n0 * K;
  for (int kt = 0; kt < K; kt += 64){
    __syncthreads();
#pragma unroll
    for (int i = 0; i < 4; ++i){
      int chunk = i * 256 + t;
      int row = chunk >> 3, cs = chunk & 7;
      int c = cs ^ (row & 7);
      GLD16(Abase + (size_t)row * K + kt + c * 8, &la[(i * 256 + w * 64) * 8]);
    }
#pragma unroll
    for (int i = 0; i < BN / 32; ++i){
      int chunk = i * 256 + t;
      int row = chunk >> 3, cs = chunk & 7;
      int c = cs ^ (row & 7);
      GLD16(Bbase + (size_t)row * K + kt + c * 8, &lb[(i * 256 + w * 64) * 8]);
    }
    asm volatile("s_waitcnt vmcnt(0)" ::: "memory");
    __syncthreads();
    short8 af[4][2], bfr[NI][2];
#pragma unroll
    for (int mi = 0; mi < 4; ++mi){
      int row = wr * 64 + mi * 16 + l15;
#pragma unroll
      for (int h = 0; h < 2; ++h)
        af[mi][h] = *(const short8*)&la[row * 64 + (((h * 4 + l4) ^ (row & 7)) * 8)];
    }
#pragma unroll
    for (int ni = 0; ni < NI; ++ni){
      int row = wc * (BN / 2) + ni * 16 + l15;
#pragma unroll
      for (int h = 0; h < 2; ++h)
        bfr[ni][h] = *(const short8*)&lb[row * 64 + (((h * 4 + l4) ^ (row & 7)) * 8)];
    }
#pragma unroll
    for (int mi = 0; mi < 4; ++mi)
#pragma unroll
      for (int ni = 0; ni < NI; ++ni){
        acc[mi][ni] = __builtin_amdgcn_mfma_f32_16x16x32_bf16(af[mi][0], bfr[ni][0], acc[mi][ni], 0, 0, 0);
        acc[mi][ni] = __builtin_amdgcn_mfma_f32_16x16x32_bf16(af[mi][1], bfr[ni][1], acc[mi][ni], 0, 0, 0);
      }
  }
#pragma unroll
  for (int mi = 0; mi < 4; ++mi){
#pragma unroll
    for (int ni = 0; ni < NI; ++ni){
#pragma unroll
      for (int r = 0; r < 4; ++r){
        int m = m0 + wr * 64 + mi * 16 + l4 * 4 + r;
        int n = n0 + wc * (BN / 2) + ni * 16 + l15;
        float v = acc[mi][ni][r] + bias[n];
        if (MODE == 0){
          int tt = n >> 10, rr = n & 1023, head = rr >> 6, d = rr & 63;
          int b = m >> 11, s = m & 2047;
          u16* dst = (tt == 0) ? oq : (tt == 1) ? okk : ov;
          dst[(((size_t)(b * 16 + head)) * 2048 + s) * 64 + d] = f2bf(v);
        } else {
          of[(size_t)m * N + n] = v;
        }
      }
    }
  }
}

// ---------------- V transpose (k-field-permuted) + per-chunk column sums ----------------
__global__ __launch_bounds__(256) void transpose_v_k(const u16* __restrict__ vb, u16* __restrict__ vt,
                                                     float* __restrict__ vpart){
  __shared__ u16 tl[64][65];
  int bh = blockIdx.x >> 5, c = blockIdx.x & 31, s0 = c * 64;
  int t = threadIdx.x;
#pragma unroll
  for (int rsub = 0; rsub < 16; ++rsub){
    int idx = rsub * 256 + t;
    int i = idx >> 6, d = idx & 63;
    tl[i][d] = vb[(((size_t)bh * 2048) + s0 + i) * 64 + d];
  }
  __syncthreads();
#pragma unroll
  for (int rsub = 0; rsub < 16; ++rsub){
    int idx = rsub * 256 + t;
    int d = idx >> 6, j = idx & 63;
    int pj = (j & 3) | (((j >> 2) & 3) << 4) | (((j >> 4) & 3) << 2);
    vt[(((size_t)bh * 64) + d) * 2048 + s0 + pj] = tl[j][d];
  }
  if (t < 64){
    float s = 0.f;
#pragma unroll 8
    for (int j = 0; j < 64; ++j) s += bf2f(tl[j][t]);
    vpart[((size_t)bh * 32 + c) * 64 + t] = s;
  }
}

// ---------------- suffix scan over V chunk sums ----------------
__global__ void vsufscan_k(const float* __restrict__ vpart, float* __restrict__ vsuf){
  int bh = blockIdx.x, d = threadIdx.x;   // 64 threads
  float run = 0.f;
  vsuf[((size_t)bh * 33 + 32) * 64 + d] = 0.f;
  for (int c = 31; c >= 0; --c){
    run += vpart[((size_t)bh * 32 + c) * 64 + d];
    vsuf[((size_t)bh * 33 + c) * 64 + d] = run;
  }
}

// ---------------- fused rel-bias causal attention (swapped-operand, cross-block split) ----------------
template<int U8, int SPLIT>
__global__ __launch_bounds__(256, 4) void attn_k(const u16* __restrict__ qb, const u16* __restrict__ kb,
                                                 const u16* __restrict__ vt, const float* __restrict__ vsuf,
                                                 const void* __restrict__ relp, const float* __restrict__ rel_emb,
                                                 u16* __restrict__ ab, float* __restrict__ pacc,
                                                 float* __restrict__ prsum){
  __shared__ u16 Kt[2][64 * 64];
  __shared__ u16 Vt[2][64 * 64];
  __shared__ float remb[64];
  const int bx = blockIdx.x, bh = blockIdx.y;
  const int p = SPLIT ? (bx >> 1) : bx;
  const int hf = SPLIT ? (bx & 1) : 0;
  const int b = bh >> 4, h = bh & 15;
  const int TA = p, TB = 31 - p;
  const int q0A = TA * 64, q0B = TB * 64;
  const int tid = threadIdx.x, w = tid >> 6, lane = tid & 63;
  const int l15 = lane & 15, l4 = lane >> 4;
  if (tid < 64) remb[tid] = rel_emb[tid * 16 + h] * (0.125f * 1.44269504088896f);
  const u16* kbh = kb + ((size_t)bh * 2048) * 64;
  const u16* vbh = vt + ((size_t)bh * 64) * 2048;
  const u16* qA = qb + (((size_t)bh * 2048) + q0A + w * 16 + l15) * 64 + l4 * 8;
  const u16* qB = qb + (((size_t)bh * 2048) + q0B + w * 16 + l15) * 64 + l4 * 8;
  const short8 aqA0 = *(const short8*)qA, aqA1 = *(const short8*)(qA + 32);
  const short8 aqB0 = *(const short8*)qB, aqB1 = *(const short8*)(qB + 32);
  const u8*  r8A  = (const u8*)relp + ((size_t)b * 2048 + q0A + w * 16 + l15) * 2048;
  const u8*  r8B  = (const u8*)relp + ((size_t)b * 2048 + q0B + w * 16 + l15) * 2048;
  const int* r32A = (const int*)relp + ((size_t)b * 2048 + q0A + w * 16 + l15) * 2048;
  const int* r32B = (const int*)relp + ((size_t)b * 2048 + q0B + w * 16 + l15) * 2048;

  const int srow0 = (tid >> 3), srow1 = 32 + (tid >> 3);
  const int scs = tid & 7;
  const int sc0 = scs ^ (srow0 & 7), sc1 = scs ^ (srow1 & 7);
  const int sldsoff = (w * 64) * 8;

#define STAGE(ktile, buf) do {                                                       \
    GLD16(kbh + (size_t)((ktile) * 64 + srow0) * 64 + sc0 * 8, &Kt[buf][sldsoff]);   \
    GLD16(kbh + (size_t)((ktile) * 64 + srow1) * 64 + sc1 * 8, &Kt[buf][2048 + sldsoff]); \
    GLD16(vbh + (size_t)srow0 * 2048 + (ktile) * 64 + sc0 * 8, &Vt[buf][sldsoff]);   \
    GLD16(vbh + (size_t)srow1 * 2048 + (ktile) * 64 + sc1 * 8, &Vt[buf][2048 + sldsoff]); \
  } while (0)

  f32x4 acc[4] = {};
  float rsum = 0.f;
  unsigned int relc[4], reln[4];

  auto relload = [&](bool isA, int kt, unsigned int* dst){
    int off = kt * 64 + 4 * l4;
    if (U8){
      const u8* pp = isA ? r8A : r8B;
#pragma unroll
      for (int t = 0; t < 4; ++t) dst[t] = *(const unsigned int*)(pp + off + 16 * t);
    } else {
      const int* pp = isA ? r32A : r32B;
#pragma unroll
      for (int t = 0; t < 4; ++t){
        int4 v4 = *(const int4*)(pp + off + 16 * t);
        dst[t] = (unsigned int)(v4.x & 255) | ((unsigned int)(v4.y & 255) << 8)
               | ((unsigned int)(v4.z & 255) << 16) | ((unsigned int)(v4.w & 255) << 24);
      }
    }
  };

  auto writeout = [&](int Td, int q0){
    asm volatile("s_nop 7\n\ts_nop 7" :::);
    float s = rsum;
    s += __shfl_xor(s, 16);
    s += __shfl_xor(s, 32);
    float invZ = 1.f / (s + (float)(2048 - (Td + 1) * 64));
    int qg = q0 + w * 16 + l15;
    const float* sufp = vsuf + ((size_t)bh * 33 + Td + 1) * 64;
#pragma unroll
    for (int ni = 0; ni < 4; ++ni){
      float4 sv = *(const float4*)(sufp + ni * 16 + 4 * l4);
      unsigned int lo2 = (unsigned int)f2bf((acc[ni][0] + sv.x) * invZ)
                       | ((unsigned int)f2bf((acc[ni][1] + sv.y) * invZ) << 16);
      unsigned int hi2 = (unsigned int)f2bf((acc[ni][2] + sv.z) * invZ)
                       | ((unsigned int)f2bf((acc[ni][3] + sv.w) * invZ) << 16);
      uint2 o; o.x = lo2; o.y = hi2;
      *(uint2*)(ab + ((size_t)b * 2048 + qg) * 1024 + h * 64 + ni * 16 + 4 * l4) = o;
    }
  };

  const int lo = (SPLIT && hf) ? 17 : 0;
  const int hi = (SPLIT && !hf) ? 17 : 33;

  {
    bool isA0 = (lo <= TA);
    int kt0 = isA0 ? lo : lo - TA - 1;
    STAGE(kt0, 0);
    relload(isA0, kt0, relc);
  }
  __syncthreads();

  for (int it = lo; it < hi; ++it){
    const bool isA = (it <= TA);
    const int kt = isA ? it : (it - TA - 1);
    const int cur = (it - lo) & 1;

    if (it + 1 < hi){
      const bool nA = (it + 1 <= TA);
      const int nkt = nA ? (it + 1) : (it - TA);
      STAGE(nkt, cur ^ 1);
      relload(nA, nkt, reln);
    }

    const short8 a0 = isA ? aqA0 : aqB0;
    const short8 a1 = isA ? aqA1 : aqB1;
    const bool diag = (kt == (isA ? TA : TB));

    short4v pk[4];
    __builtin_amdgcn_s_setprio(1);
#pragma unroll
    for (int t = 0; t < 4; ++t){
      const int krow = 16 * t + l15;
      const u16* kbase = &Kt[cur][krow * 64];
      short8 bk0 = *(const short8*)&kbase[((l4)     ^ (krow & 7)) * 8];
      short8 bk1 = *(const short8*)&kbase[((4 + l4) ^ (krow & 7)) * 8];
      f32x4 sf = {0.f, 0.f, 0.f, 0.f};
      sf = __builtin_amdgcn_mfma_f32_16x16x32_bf16(bk0, a0, sf, 0, 0, 0);
      sf = __builtin_amdgcn_mfma_f32_16x16x32_bf16(bk1, a1, sf, 0, 0, 0);
      unsigned int rw = relc[t];
      const int kk = 16 * t + 4 * l4;
      float prv[4];
#pragma unroll
      for (int r = 0; r < 4; ++r){
        float sc = sf[r] * remb[(rw >> (8 * r)) & 255];
        if (diag) sc = (kk + r <= w * 16 + l15) ? sc : 0.f;
        float pv = __builtin_amdgcn_exp2f(sc);
        rsum += pv;
        prv[r] = pv;
      }
      union { unsigned int u[2]; short4v s; } pu;
      asm("v_cvt_pk_bf16_f32 %0, %1, %2" : "=v"(pu.u[0]) : "v"(prv[0]), "v"(prv[1]));
      asm("v_cvt_pk_bf16_f32 %0, %1, %2" : "=v"(pu.u[1]) : "v"(prv[2]), "v"(prv[3]));
      pk[t] = pu.s;
    }
    asm volatile("s_nop 2" :::);
#pragma unroll
    for (int ni = 0; ni < 4; ++ni){
      const int drow = ni * 16 + l15;
      const u16* vbase = &Vt[cur][drow * 64];
      short8 vv0 = *(const short8*)&vbase[(((2 * l4)     ^ (drow & 7))) * 8];
      short8 vv1 = *(const short8*)&vbase[(((2 * l4 + 1) ^ (drow & 7))) * 8];
      short4v va0 = {vv0[0], vv0[1], vv0[2], vv0[3]};
      short4v va1 = {vv0[4], vv0[5], vv0[6], vv0[7]};
      short4v va2 = {vv1[0], vv1[1], vv1[2], vv1[3]};
      short4v va3 = {vv1[4], vv1[5], vv1[6], vv1[7]};
      acc[ni] = mfma16(va0, pk[0], acc[ni]);
      acc[ni] = mfma16(va1, pk[1], acc[ni]);
      acc[ni] = mfma16(va2, pk[2], acc[ni]);
      acc[ni] = mfma16(va3, pk[3], acc[ni]);
    }
    __builtin_amdgcn_s_setprio(0);

    if (it == TA){   // A complete (only reachable when hf==0)
      writeout(TA, q0A);
#pragma unroll
      for (int ni = 0; ni < 4; ++ni) acc[ni] = f32x4{0.f, 0.f, 0.f, 0.f};
      rsum = 0.f;
    }
    if (it + 1 < hi){
#pragma unroll
      for (int t = 0; t < 4; ++t) relc[t] = reln[t];
    }
    __syncthreads();
  }
#undef STAGE

  if (SPLIT){
    asm volatile("s_nop 7\n\ts_nop 7" :::);
    float s = rsum;
    s += __shfl_xor(s, 16);
    s += __shfl_xor(s, 32);
    const size_t slot = (((size_t)bh * 16 + p) * 2 + hf);
    float* pslot = pacc + slot * 4096;
#pragma unroll
    for (int ni = 0; ni < 4; ++ni)
      *(f32x4*)(pslot + (w * 16 + l15) * 64 + ni * 16 + 4 * l4) = acc[ni];
    if (l4 == 0) prsum[slot * 64 + w * 16 + l15] = s;
  } else {
    writeout(TB, q0B);
  }
}

// ---------------- combine B partials + suffix + normalize + store ----------------
__global__ __launch_bounds__(256) void attn_fin_k(const float* __restrict__ pacc,
                                                  const float* __restrict__ prsum,
                                                  const float* __restrict__ vsuf,
                                                  u16* __restrict__ ab){
  const int p = blockIdx.x, bh = blockIdx.y;
  const int b = bh >> 4, h = bh & 15;
  const int TB = 31 - p, q0 = TB * 64;
  const int r = threadIdx.x >> 2, cg = threadIdx.x & 3;
  const size_t slot = ((size_t)bh * 16 + p) * 2;
  const size_t base = slot * 4096 + r * 64 + cg * 16;
  float rs = prsum[slot * 64 + r] + prsum[(slot + 1) * 64 + r];
  float invZ = 1.f / (rs + (float)(2048 - (TB + 1) * 64));
  const float* sufp = vsuf + ((size_t)bh * 33 + TB + 1) * 64 + cg * 16;
  u16 o[16];
#pragma unroll
  for (int j = 0; j < 4; ++j){
    f32x4 a0 = *(const f32x4*)(pacc + base + j * 4);
    f32x4 a1 = *(const f32x4*)(pacc + base + 4096 + j * 4);
    f32x4 sv = *(const f32x4*)(sufp + j * 4);
#pragma unroll
    for (int e = 0; e < 4; ++e) o[j * 4 + e] = f2bf((a0[e] + a1[e] + sv[e]) * invZ);
  }
  u16* dst = ab + ((size_t)b * 2048 + q0 + r) * 1024 + h * 64 + cg * 16;
  *(uint4*)dst = *(const uint4*)&o[0];
  *(uint4*)(dst + 8) = *(const uint4*)&o[8];
}

// ---------------- launch ----------------
extern "C" void kernel_launch(void* const* d_in, const int* in_sizes, int n_in,
                              void* d_out, int out_size, void* d_ws, size_t ws_size,
                              hipStream_t stream){
  const float* x       = (const float*)d_in[0];
  const float* Wqkv    = (const float*)d_in[1];
  const float* bqkv    = (const float*)d_in[2];
  const float* Wproj   = (const float*)d_in[3];
  const float* bproj   = (const float*)d_in[4];
  const float* rel_emb = (const float*)d_in[5];
  const int*   rel     = (const int*)d_in[6];
  float* out = (float*)d_out;

  char* ws = (char*)d_ws;
  u16* xb     = (u16*)(ws);                      // 8 MB (x bf16; later attn output)
  u16* wqkvT  = (u16*)(ws + (8ull  << 20));      // 6 MB
  u16* wprojT = (u16*)(ws + (14ull << 20));      // 2 MB
  u16* qb     = (u16*)(ws + (16ull << 20));      // 8 MB
  u16* kb     = (u16*)(ws + (24ull << 20));      // 8 MB
  u16* vb     = (u16*)(ws + (32ull << 20));      // 8 MB
  u16* vtb    = (u16*)(ws + (40ull << 20));      // 8 MB
  float* vsuf = (float*)(ws + (48ull << 20));                   // 270 KB
  float* vpart= (float*)(ws + (48ull << 20) + (512ull << 10));  // 256 KB
  float* pacc = (float*)(ws + (49ull << 20));    // 16 MB (B partials, SPLIT only)
  float* prsum= (float*)(ws + (65ull << 20) + (512ull << 10));  // 256 KB
  u8*   rel8  = (u8*)(ws + (66ull << 20));       // 8.4 MB
  const bool useSplit = ws_size >= (67ull << 20);
  const bool useU8    = ws_size >= (75ull << 20);

  prep_k<<<useU8 ? 16384 : 8192, 256, 0, stream>>>(x, xb, Wqkv, wqkvT, Wproj, wprojT, rel, rel8);
  gemm_bt_k<128, 0><<<dim3(24, 32), 256, 0, stream>>>(xb, wqkvT, bqkv, qb, kb, vb, nullptr, 4096, 3072, 1024);
  transpose_v_k<<<1024, 256, 0, stream>>>(vb, vtb, vpart);
  vsufscan_k<<<32, 64, 0, stream>>>(vpart, vsuf);
  if (useU8)
    attn_k<1, 1><<<dim3(32, 32), 256, 0, stream>>>(qb, kb, vtb, vsuf, rel8, rel_emb, xb, pacc, prsum);
  else if (useSplit)
    attn_k<0, 1><<<dim3(32, 32), 256, 0, stream>>>(qb, kb, vtb, vsuf, rel, rel_emb, xb, pacc, prsum);
  else
    attn_k<0, 0><<<dim3(16, 32), 256, 0, stream>>>(qb, kb, vtb, vsuf, rel, rel_emb, xb, pacc, prsum);
  if (useSplit || useU8)
    attn_fin_k<<<dim3(16, 32), 256, 0, stream>>>(pacc, prsum, vsuf, xb);
  gemm_bt_k<64, 1><<<dim3(16, 32), 256, 0, stream>>>(xb, wprojT, bproj, nullptr, nullptr, nullptr, out, 4096, 1024, 1024);
}

// Round 8
// 143.602 us; speedup vs baseline: 1.3316x; 1.0206x over previous
//
#include <hip/hip_runtime.h>

typedef unsigned short u16;
typedef unsigned char u8;
typedef __attribute__((ext_vector_type(8))) short short8;
typedef __attribute__((ext_vector_type(4))) short short4v;
typedef __attribute__((ext_vector_type(4))) float f32x4;

#define GLD16(g, l) __builtin_amdgcn_global_load_lds( \
    (const __attribute__((address_space(1))) void*)(g), \
    (__attribute__((address_space(3))) void*)(l), 16, 0, 0)

__device__ __forceinline__ float bf2f(u16 u){
  union { unsigned int i; float f; } v; v.i = ((unsigned int)u) << 16; return v.f;
}
__device__ __forceinline__ u16 f2bf(float f){
  union { float f; unsigned int i; } v; v.f = f;
  unsigned int u = v.i;
  unsigned int r = (u + 0x7FFFu + ((u >> 16) & 1u)) >> 16;
  return (u16)r;
}

__device__ __forceinline__ f32x4 mfma16(short4v a, short4v b, f32x4 c){
#if __has_builtin(__builtin_amdgcn_mfma_f32_16x16x16bf16_1k)
  return __builtin_amdgcn_mfma_f32_16x16x16bf16_1k(a, b, c, 0, 0, 0);
#else
  asm volatile("s_nop 1\n\tv_mfma_f32_16x16x16_bf16 %0, %1, %2, %0" : "+v"(c) : "v"(a), "v"(b));
  return c;
#endif
}

// ---------------- fused prep: x->bf16 | Wqkv^T | Wproj^T | rel->u8 ----------------
__global__ __launch_bounds__(256) void prep_k(const float* __restrict__ x, u16* __restrict__ xb,
                                              const float* __restrict__ Wqkv, u16* __restrict__ wqkvT,
                                              const float* __restrict__ Wproj, u16* __restrict__ wprojT,
                                              const int* __restrict__ rel, u8* __restrict__ rel8){
  const int bid = blockIdx.x, t = threadIdx.x;
  if (bid < 4096){
    int i = bid * 256 + t;
    float4 v = ((const float4*)x)[i];
    unsigned long long pk = (unsigned long long)f2bf(v.x)
      | ((unsigned long long)f2bf(v.y) << 16)
      | ((unsigned long long)f2bf(v.z) << 32)
      | ((unsigned long long)f2bf(v.w) << 48);
    ((unsigned long long*)xb)[i] = pk;
  } else if (bid < 8192){
    const float* W; u16* Wt; int K, N, blk, nbx;
    if (bid < 7168){ W = Wqkv; Wt = wqkvT; K = 1024; N = 3072; blk = bid - 4096; nbx = 96; }
    else           { W = Wproj; Wt = wprojT; K = 1024; N = 1024; blk = bid - 7168; nbx = 32; }
    __shared__ float tl[32][33];
    int n0 = (blk % nbx) * 32, k0 = (blk / nbx) * 32;
    int tx = t & 31, ty = t >> 5;
    for (int i = ty; i < 32; i += 8)
      tl[i][tx] = W[(size_t)(k0 + i) * N + n0 + tx];
    __syncthreads();
    for (int i = ty; i < 32; i += 8)
      Wt[(size_t)(n0 + i) * K + k0 + tx] = f2bf(tl[tx][i]);
  } else {
    int i = (bid - 8192) * 256 + t;
    int4 v = ((const int4*)rel)[i];
    unsigned int pk = (unsigned int)(v.x & 255) | ((unsigned int)(v.y & 255) << 8)
      | ((unsigned int)(v.z & 255) << 16) | ((unsigned int)(v.w & 255) << 24);
    ((unsigned int*)rel8)[i] = pk;
  }
}

// ---------------- bf16 GEMM (B^T input), BK=64, XOR-swizzled LDS ----------------
template<int BN, int MODE>
__global__ __launch_bounds__(256) void gemm_bt_k(const u16* __restrict__ A, const u16* __restrict__ Bt,
                                                 const float* __restrict__ bias,
                                                 u16* __restrict__ oq, u16* __restrict__ okk, u16* __restrict__ ov,
                                                 float* __restrict__ of,
                                                 int M, int N, int K){
  __shared__ u16 la[128 * 64];
  __shared__ u16 lb[BN * 64];
  const int t = threadIdx.x, w = t >> 6, lane = t & 63;
  const int l15 = lane & 15, l4 = lane >> 4;
  const int m0 = blockIdx.y * 128, n0 = blockIdx.x * BN;
  const int wr = w >> 1, wc = w & 1;
  constexpr int NI = BN / 32;
  f32x4 acc[4][NI] = {};
  const u16* Abase = A + (size_t)m0 * K;
  const u16* Bbase = Bt + (size_t)n0 * K;
  for (int kt = 0; kt < K; kt += 64){
    __syncthreads();
#pragma unroll
    for (int i = 0; i < 4; ++i){
      int chunk = i * 256 + t;
      int row = chunk >> 3, cs = chunk & 7;
      int c = cs ^ (row & 7);
      GLD16(Abase + (size_t)row * K + kt + c * 8, &la[(i * 256 + w * 64) * 8]);
    }
#pragma unroll
    for (int i = 0; i < BN / 32; ++i){
      int chunk = i * 256 + t;
      int row = chunk >> 3, cs = chunk & 7;
      int c = cs ^ (row & 7);
      GLD16(Bbase + (size_t)row * K + kt + c * 8, &lb[(i * 256 + w * 64) * 8]);
    }
    asm volatile("s_waitcnt vmcnt(0)" ::: "memory");
    __syncthreads();
    short8 af[4][2], bfr[NI][2];
#pragma unroll
    for (int mi = 0; mi < 4; ++mi){
      int row = wr * 64 + mi * 16 + l15;
#pragma unroll
      for (int h = 0; h < 2; ++h)
        af[mi][h] = *(const short8*)&la[row * 64 + (((h * 4 + l4) ^ (row & 7)) * 8)];
    }
#pragma unroll
    for (int ni = 0; ni < NI; ++ni){
      int row = wc * (BN / 2) + ni * 16 + l15;
#pragma unroll
      for (int h = 0; h < 2; ++h)
        bfr[ni][h] = *(const short8*)&lb[row * 64 + (((h * 4 + l4) ^ (row & 7)) * 8)];
    }
#pragma unroll
    for (int mi = 0; mi < 4; ++mi)
#pragma unroll
      for (int ni = 0; ni < NI; ++ni){
        acc[mi][ni] = __builtin_amdgcn_mfma_f32_16x16x32_bf16(af[mi][0], bfr[ni][0], acc[mi][ni], 0, 0, 0);
        acc[mi][ni] = __builtin_amdgcn_mfma_f32_16x16x32_bf16(af[mi][1], bfr[ni][1], acc[mi][ni], 0, 0, 0);
      }
  }
#pragma unroll
  for (int mi = 0; mi < 4; ++mi){
#pragma unroll
    for (int ni = 0; ni < NI; ++ni){
#pragma unroll
      for (int r = 0; r < 4; ++r){
        int m = m0 + wr * 64 + mi * 16 + l4 * 4 + r;
        int n = n0 + wc * (BN / 2) + ni * 16 + l15;
        float v = acc[mi][ni][r] + bias[n];
        if (MODE == 0){
          int tt = n >> 10, rr = n & 1023, head = rr >> 6, d = rr & 63;
          int b = m >> 11, s = m & 2047;
          u16* dst = (tt == 0) ? oq : (tt == 1) ? okk : ov;
          dst[(((size_t)(b * 16 + head)) * 2048 + s) * 64 + d] = f2bf(v);
        } else {
          of[(size_t)m * N + n] = v;
        }
      }
    }
  }
}

// ---------------- V transpose (k-field-permuted) + per-chunk column sums ----------------
__global__ __launch_bounds__(256) void transpose_v_k(const u16* __restrict__ vb, u16* __restrict__ vt,
                                                     float* __restrict__ vpart){
  __shared__ u16 tl[64][65];
  int bh = blockIdx.x >> 5, c = blockIdx.x & 31, s0 = c * 64;
  int t = threadIdx.x;
#pragma unroll
  for (int rsub = 0; rsub < 16; ++rsub){
    int idx = rsub * 256 + t;
    int i = idx >> 6, d = idx & 63;
    tl[i][d] = vb[(((size_t)bh * 2048) + s0 + i) * 64 + d];
  }
  __syncthreads();
#pragma unroll
  for (int rsub = 0; rsub < 16; ++rsub){
    int idx = rsub * 256 + t;
    int d = idx >> 6, j = idx & 63;
    int pj = (j & 3) | (((j >> 2) & 3) << 4) | (((j >> 4) & 3) << 2);
    vt[(((size_t)bh * 64) + d) * 2048 + s0 + pj] = tl[j][d];
  }
  if (t < 64){
    float s = 0.f;
#pragma unroll 8
    for (int j = 0; j < 64; ++j) s += bf2f(tl[j][t]);
    vpart[((size_t)bh * 32 + c) * 64 + t] = s;
  }
}

// ---------------- suffix scan over V chunk sums ----------------
__global__ void vsufscan_k(const float* __restrict__ vpart, float* __restrict__ vsuf){
  int bh = blockIdx.x, d = threadIdx.x;   // 64 threads
  float run = 0.f;
  vsuf[((size_t)bh * 33 + 32) * 64 + d] = 0.f;
  for (int c = 31; c >= 0; --c){
    run += vpart[((size_t)bh * 32 + c) * 64 + d];
    vsuf[((size_t)bh * 33 + c) * 64 + d] = run;
  }
}

// ---------------- fused rel-bias causal attention (swapped-operand, cross-block split) ----------------
// SPLIT=1: 1-D grid of 1024, XCD-swizzled: lid = pf*32 + within*8 + bhgrp,
//   so all 32 (p,hf)-blocks of one bh satisfy lid%8 == bhgrp -> same XCD
//   (HW round-robins dispatch id over 8 XCDs). Each XCD serves bh in
//   [bhgrp*4, bhgrp*4+4): 2 MB of K/V -> L2-resident staging.
template<int U8, int SPLIT>
__global__ __launch_bounds__(256, 4) void attn_k(const u16* __restrict__ qb, const u16* __restrict__ kb,
                                                 const u16* __restrict__ vt, const float* __restrict__ vsuf,
                                                 const void* __restrict__ relp, const float* __restrict__ rel_emb,
                                                 u16* __restrict__ ab, float* __restrict__ pacc,
                                                 float* __restrict__ prsum){
  __shared__ u16 Kt[2][64 * 64];
  __shared__ u16 Vt[2][64 * 64];
  __shared__ float remb[64];
  int p, hf, bh;
  if (SPLIT){
    const int lid = blockIdx.x;
    const int bhgrp = lid & 7, within = (lid >> 3) & 3, pf = lid >> 5;
    bh = bhgrp * 4 + within;
    p = pf >> 1; hf = pf & 1;
  } else {
    p = blockIdx.x; hf = 0; bh = blockIdx.y;
  }
  const int b = bh >> 4, h = bh & 15;
  const int TA = p, TB = 31 - p;
  const int q0A = TA * 64, q0B = TB * 64;
  const int tid = threadIdx.x, w = tid >> 6, lane = tid & 63;
  const int l15 = lane & 15, l4 = lane >> 4;
  if (tid < 64) remb[tid] = rel_emb[tid * 16 + h] * (0.125f * 1.44269504088896f);
  const u16* kbh = kb + ((size_t)bh * 2048) * 64;
  const u16* vbh = vt + ((size_t)bh * 64) * 2048;
  const u16* qA = qb + (((size_t)bh * 2048) + q0A + w * 16 + l15) * 64 + l4 * 8;
  const u16* qB = qb + (((size_t)bh * 2048) + q0B + w * 16 + l15) * 64 + l4 * 8;
  const short8 aqA0 = *(const short8*)qA, aqA1 = *(const short8*)(qA + 32);
  const short8 aqB0 = *(const short8*)qB, aqB1 = *(const short8*)(qB + 32);
  const u8*  r8A  = (const u8*)relp + ((size_t)b * 2048 + q0A + w * 16 + l15) * 2048;
  const u8*  r8B  = (const u8*)relp + ((size_t)b * 2048 + q0B + w * 16 + l15) * 2048;
  const int* r32A = (const int*)relp + ((size_t)b * 2048 + q0A + w * 16 + l15) * 2048;
  const int* r32B = (const int*)relp + ((size_t)b * 2048 + q0B + w * 16 + l15) * 2048;

  const int srow0 = (tid >> 3), srow1 = 32 + (tid >> 3);
  const int scs = tid & 7;
  const int sc0 = scs ^ (srow0 & 7), sc1 = scs ^ (srow1 & 7);
  const int sldsoff = (w * 64) * 8;

#define STAGE(ktile, buf) do {                                                       \
    GLD16(kbh + (size_t)((ktile) * 64 + srow0) * 64 + sc0 * 8, &Kt[buf][sldsoff]);   \
    GLD16(kbh + (size_t)((ktile) * 64 + srow1) * 64 + sc1 * 8, &Kt[buf][2048 + sldsoff]); \
    GLD16(vbh + (size_t)srow0 * 2048 + (ktile) * 64 + sc0 * 8, &Vt[buf][sldsoff]);   \
    GLD16(vbh + (size_t)srow1 * 2048 + (ktile) * 64 + sc1 * 8, &Vt[buf][2048 + sldsoff]); \
  } while (0)

  f32x4 acc[4] = {};
  float rsum = 0.f;
  unsigned int relc[4], reln[4];

  auto relload = [&](bool isA, int kt, unsigned int* dst){
    int off = kt * 64 + 4 * l4;
    if (U8){
      const u8* pp = isA ? r8A : r8B;
#pragma unroll
      for (int t = 0; t < 4; ++t) dst[t] = *(const unsigned int*)(pp + off + 16 * t);
    } else {
      const int* pp = isA ? r32A : r32B;
#pragma unroll
      for (int t = 0; t < 4; ++t){
        int4 v4 = *(const int4*)(pp + off + 16 * t);
        dst[t] = (unsigned int)(v4.x & 255) | ((unsigned int)(v4.y & 255) << 8)
               | ((unsigned int)(v4.z & 255) << 16) | ((unsigned int)(v4.w & 255) << 24);
      }
    }
  };

  auto writeout = [&](int Td, int q0){
    asm volatile("s_nop 7\n\ts_nop 7" :::);
    float s = rsum;
    s += __shfl_xor(s, 16);
    s += __shfl_xor(s, 32);
    float invZ = 1.f / (s + (float)(2048 - (Td + 1) * 64));
    int qg = q0 + w * 16 + l15;
    const float* sufp = vsuf + ((size_t)bh * 33 + Td + 1) * 64;
#pragma unroll
    for (int ni = 0; ni < 4; ++ni){
      float4 sv = *(const float4*)(sufp + ni * 16 + 4 * l4);
      unsigned int lo2 = (unsigned int)f2bf((acc[ni][0] + sv.x) * invZ)
                       | ((unsigned int)f2bf((acc[ni][1] + sv.y) * invZ) << 16);
      unsigned int hi2 = (unsigned int)f2bf((acc[ni][2] + sv.z) * invZ)
                       | ((unsigned int)f2bf((acc[ni][3] + sv.w) * invZ) << 16);
      uint2 o; o.x = lo2; o.y = hi2;
      *(uint2*)(ab + ((size_t)b * 2048 + qg) * 1024 + h * 64 + ni * 16 + 4 * l4) = o;
    }
  };

  const int lo = (SPLIT && hf) ? 17 : 0;
  const int hi = (SPLIT && !hf) ? 17 : 33;

  {
    bool isA0 = (lo <= TA);
    int kt0 = isA0 ? lo : lo - TA - 1;
    STAGE(kt0, 0);
    relload(isA0, kt0, relc);
  }
  __syncthreads();

  for (int it = lo; it < hi; ++it){
    const bool isA = (it <= TA);
    const int kt = isA ? it : (it - TA - 1);
    const int cur = (it - lo) & 1;

    if (it + 1 < hi){
      const bool nA = (it + 1 <= TA);
      const int nkt = nA ? (it + 1) : (it - TA);
      STAGE(nkt, cur ^ 1);
      relload(nA, nkt, reln);
    }

    const short8 a0 = isA ? aqA0 : aqB0;
    const short8 a1 = isA ? aqA1 : aqB1;
    const bool diag = (kt == (isA ? TA : TB));

    short4v pk[4];
    __builtin_amdgcn_s_setprio(1);
#pragma unroll
    for (int t = 0; t < 4; ++t){
      const int krow = 16 * t + l15;
      const u16* kbase = &Kt[cur][krow * 64];
      short8 bk0 = *(const short8*)&kbase[((l4)     ^ (krow & 7)) * 8];
      short8 bk1 = *(const short8*)&kbase[((4 + l4) ^ (krow & 7)) * 8];
      f32x4 sf = {0.f, 0.f, 0.f, 0.f};
      sf = __builtin_amdgcn_mfma_f32_16x16x32_bf16(bk0, a0, sf, 0, 0, 0);
      sf = __builtin_amdgcn_mfma_f32_16x16x32_bf16(bk1, a1, sf, 0, 0, 0);
      unsigned int rw = relc[t];
      const int kk = 16 * t + 4 * l4;
      float prv[4];
#pragma unroll
      for (int r = 0; r < 4; ++r){
        float sc = sf[r] * remb[(rw >> (8 * r)) & 255];
        if (diag) sc = (kk + r <= w * 16 + l15) ? sc : 0.f;
        float pv = __builtin_amdgcn_exp2f(sc);
        rsum += pv;
        prv[r] = pv;
      }
      union { unsigned int u[2]; short4v s; } pu;
      asm("v_cvt_pk_bf16_f32 %0, %1, %2" : "=v"(pu.u[0]) : "v"(prv[0]), "v"(prv[1]));
      asm("v_cvt_pk_bf16_f32 %0, %1, %2" : "=v"(pu.u[1]) : "v"(prv[2]), "v"(prv[3]));
      pk[t] = pu.s;
    }
    asm volatile("s_nop 2" :::);
#pragma unroll
    for (int ni = 0; ni < 4; ++ni){
      const int drow = ni * 16 + l15;
      const u16* vbase = &Vt[cur][drow * 64];
      short8 vv0 = *(const short8*)&vbase[(((2 * l4)     ^ (drow & 7))) * 8];
      short8 vv1 = *(const short8*)&vbase[(((2 * l4 + 1) ^ (drow & 7))) * 8];
      short4v va0 = {vv0[0], vv0[1], vv0[2], vv0[3]};
      short4v va1 = {vv0[4], vv0[5], vv0[6], vv0[7]};
      short4v va2 = {vv1[0], vv1[1], vv1[2], vv1[3]};
      short4v va3 = {vv1[4], vv1[5], vv1[6], vv1[7]};
      acc[ni] = mfma16(va0, pk[0], acc[ni]);
      acc[ni] = mfma16(va1, pk[1], acc[ni]);
      acc[ni] = mfma16(va2, pk[2], acc[ni]);
      acc[ni] = mfma16(va3, pk[3], acc[ni]);
    }
    __builtin_amdgcn_s_setprio(0);

    if (it == TA){   // A complete (only reachable when hf==0)
      writeout(TA, q0A);
#pragma unroll
      for (int ni = 0; ni < 4; ++ni) acc[ni] = f32x4{0.f, 0.f, 0.f, 0.f};
      rsum = 0.f;
    }
    if (it + 1 < hi){
#pragma unroll
      for (int t = 0; t < 4; ++t) relc[t] = reln[t];
    }
    __syncthreads();
  }
#undef STAGE

  if (SPLIT){
    asm volatile("s_nop 7\n\ts_nop 7" :::);
    float s = rsum;
    s += __shfl_xor(s, 16);
    s += __shfl_xor(s, 32);
    const size_t slot = (((size_t)bh * 16 + p) * 2 + hf);
    float* pslot = pacc + slot * 4096;
#pragma unroll
    for (int ni = 0; ni < 4; ++ni)
      *(f32x4*)(pslot + (w * 16 + l15) * 64 + ni * 16 + 4 * l4) = acc[ni];
    if (l4 == 0) prsum[slot * 64 + w * 16 + l15] = s;
  } else {
    writeout(TB, q0B);
  }
}

// ---------------- combine B partials + suffix + normalize + store ----------------
__global__ __launch_bounds__(256) void attn_fin_k(const float* __restrict__ pacc,
                                                  const float* __restrict__ prsum,
                                                  const float* __restrict__ vsuf,
                                                  u16* __restrict__ ab){
  const int p = blockIdx.x, bh = blockIdx.y;
  const int b = bh >> 4, h = bh & 15;
  const int TB = 31 - p, q0 = TB * 64;
  const int r = threadIdx.x >> 2, cg = threadIdx.x & 3;
  const size_t slot = ((size_t)bh * 16 + p) * 2;
  const size_t base = slot * 4096 + r * 64 + cg * 16;
  float rs = prsum[slot * 64 + r] + prsum[(slot + 1) * 64 + r];
  float invZ = 1.f / (rs + (float)(2048 - (TB + 1) * 64));
  const float* sufp = vsuf + ((size_t)bh * 33 + TB + 1) * 64 + cg * 16;
  u16 o[16];
#pragma unroll
  for (int j = 0; j < 4; ++j){
    f32x4 a0 = *(const f32x4*)(pacc + base + j * 4);
    f32x4 a1 = *(const f32x4*)(pacc + base + 4096 + j * 4);
    f32x4 sv = *(const f32x4*)(sufp + j * 4);
#pragma unroll
    for (int e = 0; e < 4; ++e) o[j * 4 + e] = f2bf((a0[e] + a1[e] + sv[e]) * invZ);
  }
  u16* dst = ab + ((size_t)b * 2048 + q0 + r) * 1024 + h * 64 + cg * 16;
  *(uint4*)dst = *(const uint4*)&o[0];
  *(uint4*)(dst + 8) = *(const uint4*)&o[8];
}

// ---------------- launch ----------------
extern "C" void kernel_launch(void* const* d_in, const int* in_sizes, int n_in,
                              void* d_out, int out_size, void* d_ws, size_t ws_size,
                              hipStream_t stream){
  const float* x       = (const float*)d_in[0];
  const float* Wqkv    = (const float*)d_in[1];
  const float* bqkv    = (const float*)d_in[2];
  const float* Wproj   = (const float*)d_in[3];
  const float* bproj   = (const float*)d_in[4];
  const float* rel_emb = (const float*)d_in[5];
  const int*   rel     = (const int*)d_in[6];
  float* out = (float*)d_out;

  char* ws = (char*)d_ws;
  u16* xb     = (u16*)(ws);                      // 8 MB (x bf16; later attn output)
  u16* wqkvT  = (u16*)(ws + (8ull  << 20));      // 6 MB
  u16* wprojT = (u16*)(ws + (14ull << 20));      // 2 MB
  u16* qb     = (u16*)(ws + (16ull << 20));      // 8 MB
  u16* kb     = (u16*)(ws + (24ull << 20));      // 8 MB
  u16* vb     = (u16*)(ws + (32ull << 20));      // 8 MB
  u16* vtb    = (u16*)(ws + (40ull << 20));      // 8 MB
  float* vsuf = (float*)(ws + (48ull << 20));                   // 270 KB
  float* vpart= (float*)(ws + (48ull << 20) + (512ull << 10));  // 256 KB
  float* pacc = (float*)(ws + (49ull << 20));    // 16 MB (B partials, SPLIT only)
  float* prsum= (float*)(ws + (65ull << 20) + (512ull << 10));  // 256 KB
  u8*   rel8  = (u8*)(ws + (66ull << 20));       // 8.4 MB
  const bool useSplit = ws_size >= (67ull << 20);
  const bool useU8    = ws_size >= (75ull << 20);

  prep_k<<<useU8 ? 16384 : 8192, 256, 0, stream>>>(x, xb, Wqkv, wqkvT, Wproj, wprojT, rel, rel8);
  gemm_bt_k<128, 0><<<dim3(24, 32), 256, 0, stream>>>(xb, wqkvT, bqkv, qb, kb, vb, nullptr, 4096, 3072, 1024);
  transpose_v_k<<<1024, 256, 0, stream>>>(vb, vtb, vpart);
  vsufscan_k<<<32, 64, 0, stream>>>(vpart, vsuf);
  if (useU8)
    attn_k<1, 1><<<dim3(1024), 256, 0, stream>>>(qb, kb, vtb, vsuf, rel8, rel_emb, xb, pacc, prsum);
  else if (useSplit)
    attn_k<0, 1><<<dim3(1024), 256, 0, stream>>>(qb, kb, vtb, vsuf, rel, rel_emb, xb, pacc, prsum);
  else
    attn_k<0, 0><<<dim3(16, 32), 256, 0, stream>>>(qb, kb, vtb, vsuf, rel, rel_emb, xb, pacc, prsum);
  if (useSplit || useU8)
    attn_fin_k<<<dim3(16, 32), 256, 0, stream>>>(pacc, prsum, vsuf, xb);
  gemm_bt_k<64, 1><<<dim3(16, 32), 256, 0, stream>>>(xb, wprojT, bproj, nullptr, nullptr, nullptr, out, 4096, 1024, 1024);
}